// Round 8
// baseline (1176.988 us; speedup 1.0000x reference)
//
#include <hip/hip_runtime.h>

#define BB 256
#define TT 1024
#define II 128
#define HH 64
#define BT (BB * TT)
#define NBLK 16   // core blocks, 16 batch columns each

typedef _Float16 h2 __attribute__((ext_vector_type(2)));
typedef _Float16 half8 __attribute__((ext_vector_type(8)));
typedef float f32x4 __attribute__((ext_vector_type(4)));
typedef unsigned int uint;
typedef unsigned short ushort;

#define BC(u) __builtin_bit_cast(h2, (uint)(u))
#define MFMA16(a, b, c) __builtin_amdgcn_mfma_f32_16x16x32_f16((a), (b), (c), 0, 0, 0)
#define SIG(v) __builtin_amdgcn_rcpf(1.0f + __expf(-(v)))
#define TNH(v) (1.0f - 2.0f * __builtin_amdgcn_rcpf(1.0f + __expf(2.0f * (v))))

__device__ __forceinline__ half8 lda8(const float* p) {
    float4 f0 = ((const float4*)p)[0], f1 = ((const float4*)p)[1];
    half8 h;
    h[0]=(_Float16)f0.x; h[1]=(_Float16)f0.y; h[2]=(_Float16)f0.z; h[3]=(_Float16)f0.w;
    h[4]=(_Float16)f1.x; h[5]=(_Float16)f1.y; h[6]=(_Float16)f1.z; h[7]=(_Float16)f1.w;
    return h;
}

// activation for one lane's 4 (j,b) pairs: all 4 gates in-lane (MFMA C layout)
__device__ __forceinline__ uint2 lstm_act(f32x4 ai, f32x4 af, f32x4 ag, f32x4 ao,
                                          f32x4* cs) {
    f32x4 c = *cs;
    float hh0, hh1, hh2, hh3;
#define ONE(r, dst) { float ii = SIG(ai[r]); float ff = SIG(af[r]); \
    float gg = TNH(ag[r]); float oo = SIG(ao[r]); \
    c[r] = fmaf(ff, c[r], ii * gg); dst = oo * TNH(c[r]); }
    ONE(0, hh0) ONE(1, hh1) ONE(2, hh2) ONE(3, hh3)
#undef ONE
    *cs = c;
    h2 pa; pa[0] = (_Float16)hh0; pa[1] = (_Float16)hh1;
    h2 pb; pb[0] = (_Float16)hh2; pb[1] = (_Float16)hh3;
    uint2 r; r.x = __builtin_bit_cast(uint, pa); r.y = __builtin_bit_cast(uint, pb);
    return r;
}

// ============ Kernel A: xg[bt][r] = x[bt,:] . w_ih0[r,:]  (f16) — R7, passed ====
__global__ __launch_bounds__(256)
void xg_mfma(const float* __restrict__ x, const float* __restrict__ w_ih0,
             ushort* __restrict__ xg)
{
    __shared__ __align__(16) _Float16 xt[64][136];
    __shared__ __align__(16) _Float16 wt[128][136];
    const int tid = threadIdx.x, lane = tid & 63, wv = tid >> 6;
    const int bt0 = blockIdx.x * 64;
    {
        const int row = tid >> 2, q = (tid & 3) * 32;
        const float4* src = (const float4*)(x + (size_t)(bt0 + row) * II + q);
        _Float16* dst = &xt[row][q];
        #pragma unroll
        for (int i = 0; i < 8; ++i) {
            float4 v = src[i];
            dst[4*i+0]=(_Float16)v.x; dst[4*i+1]=(_Float16)v.y;
            dst[4*i+2]=(_Float16)v.z; dst[4*i+3]=(_Float16)v.w;
        }
    }
    for (int nh = 0; nh < 2; ++nh) {
        __syncthreads();
        {
            const int n = tid >> 1, kh = (tid & 1) * 64;
            const float4* src = (const float4*)(w_ih0 + (size_t)(nh * 128 + n) * II + kh);
            _Float16* dst = &wt[n][kh];
            #pragma unroll
            for (int i = 0; i < 16; ++i) {
                float4 v = src[i];
                dst[4*i+0]=(_Float16)v.x; dst[4*i+1]=(_Float16)v.y;
                dst[4*i+2]=(_Float16)v.z; dst[4*i+3]=(_Float16)v.w;
            }
        }
        __syncthreads();
        const int m = wv * 16 + (lane & 15);
        const int kf = (lane >> 4) * 8;
        half8 a0 = *(const half8*)&xt[m][ 0 + kf];
        half8 a1 = *(const half8*)&xt[m][32 + kf];
        half8 a2 = *(const half8*)&xt[m][64 + kf];
        half8 a3 = *(const half8*)&xt[m][96 + kf];
        #pragma unroll
        for (int nt = 0; nt < 8; ++nt) {
            const int nloc = nt * 16 + (lane & 15);
            half8 b0 = *(const half8*)&wt[nloc][ 0 + kf];
            half8 b1 = *(const half8*)&wt[nloc][32 + kf];
            half8 b2 = *(const half8*)&wt[nloc][64 + kf];
            half8 b3 = *(const half8*)&wt[nloc][96 + kf];
            f32x4 acc = {0.f, 0.f, 0.f, 0.f};
            acc = MFMA16(a0, b0, acc); acc = MFMA16(a1, b1, acc);
            acc = MFMA16(a2, b2, acc); acc = MFMA16(a3, b3, acc);
            const int col = nh * 128 + nt * 16 + (lane & 15);
            const int r0  = wv * 16 + (lane >> 4) * 4;
            #pragma unroll
            for (int r = 0; r < 4; ++r) {
                _Float16 hv = (_Float16)acc[r];
                xg[(size_t)(bt0 + r0 + r) * 256 + col] = __builtin_bit_cast(ushort, hv);
            }
        }
    }
}

// ============ Kernel B: MFMA recurrence, 16 batch cols per block ==============
// Waves 0-3: h0(k) = lstm0(xg(k), h0(k-1)); A = W_hh0 (K=64).
// Waves 4-7: h1(k-1) = lstm1(h0(k-1), h1(k-2)); A = [W_ih1 | W_hh1] (K=128).
// A-frags live in registers/AGPRs (MFMA reads AGPRs natively — no moves).
// B-frags = h-state from LDS [b][j] f16 (stride 72, aligned b128).
// C layout puts gates i,f,g,o of (j,b) in ONE lane -> in-lane c/h, no shuffles.
// xg enters as C-init (bias + prefetched dwordx2). One barrier/step.
__global__ __launch_bounds__(512) __attribute__((amdgpu_waves_per_eu(2, 2)))
void lstm2_core(const float* __restrict__ w_hh0,
                const float* __restrict__ b_ih0, const float* __restrict__ b_hh0,
                const float* __restrict__ w_ih1, const float* __restrict__ w_hh1,
                const float* __restrict__ b_ih1, const float* __restrict__ b_hh1,
                const ushort* __restrict__ xg, ushort* __restrict__ h1g)
{
    const int bb   = blockIdx.x;
    const int tid  = threadIdx.x;
    const int w    = tid >> 6, l = tid & 63;
    const int wl   = w & 3;
    const bool isL0 = (w < 4);
    const int b    = l & 15;            // batch col (B-frag n / C col)
    const int quad = l >> 4;
    const int mrow = 16 * wl + b;       // A-frag m row (m = lane&15)
    const int qk   = quad * 8;          // k-octet offset (A and B)
    const int j0   = 16 * wl + quad * 4; // C rows owned

    __shared__ __align__(16) _Float16 h0sh[2][16][72];
    __shared__ __align__(16) _Float16 h1sh[2][16][72];

    // ---- A fragments (weights, f16) ----
    half8 F00={},F01={},F02={},F03={}, F10={},F11={},F12={},F13={};
    half8 F20={},F21={},F22={},F23={}, F30={},F31={},F32={},F33={};
    if (isL0) {
        F00 = lda8(w_hh0 + (size_t)(  0 + mrow) * HH + qk);
        F01 = lda8(w_hh0 + (size_t)(  0 + mrow) * HH + 32 + qk);
        F10 = lda8(w_hh0 + (size_t)( 64 + mrow) * HH + qk);
        F11 = lda8(w_hh0 + (size_t)( 64 + mrow) * HH + 32 + qk);
        F20 = lda8(w_hh0 + (size_t)(128 + mrow) * HH + qk);
        F21 = lda8(w_hh0 + (size_t)(128 + mrow) * HH + 32 + qk);
        F30 = lda8(w_hh0 + (size_t)(192 + mrow) * HH + qk);
        F31 = lda8(w_hh0 + (size_t)(192 + mrow) * HH + 32 + qk);
    } else {
        F00 = lda8(w_ih1 + (size_t)(  0 + mrow) * HH + qk);
        F01 = lda8(w_ih1 + (size_t)(  0 + mrow) * HH + 32 + qk);
        F02 = lda8(w_hh1 + (size_t)(  0 + mrow) * HH + qk);
        F03 = lda8(w_hh1 + (size_t)(  0 + mrow) * HH + 32 + qk);
        F10 = lda8(w_ih1 + (size_t)( 64 + mrow) * HH + qk);
        F11 = lda8(w_ih1 + (size_t)( 64 + mrow) * HH + 32 + qk);
        F12 = lda8(w_hh1 + (size_t)( 64 + mrow) * HH + qk);
        F13 = lda8(w_hh1 + (size_t)( 64 + mrow) * HH + 32 + qk);
        F20 = lda8(w_ih1 + (size_t)(128 + mrow) * HH + qk);
        F21 = lda8(w_ih1 + (size_t)(128 + mrow) * HH + 32 + qk);
        F22 = lda8(w_hh1 + (size_t)(128 + mrow) * HH + qk);
        F23 = lda8(w_hh1 + (size_t)(128 + mrow) * HH + 32 + qk);
        F30 = lda8(w_ih1 + (size_t)(192 + mrow) * HH + qk);
        F31 = lda8(w_ih1 + (size_t)(192 + mrow) * HH + 32 + qk);
        F32 = lda8(w_hh1 + (size_t)(192 + mrow) * HH + qk);
        F33 = lda8(w_hh1 + (size_t)(192 + mrow) * HH + 32 + qk);
    }
    asm volatile("" : "+v"(F00),"+v"(F01),"+v"(F02),"+v"(F03),
                      "+v"(F10),"+v"(F11),"+v"(F12),"+v"(F13),
                      "+v"(F20),"+v"(F21),"+v"(F22),"+v"(F23),
                      "+v"(F30),"+v"(F31),"+v"(F32),"+v"(F33));

    // ---- biases (rows j0..j0+3 of each gate) ----
    const float* bi = isL0 ? b_ih0 : b_ih1;
    const float* bh = isL0 ? b_hh0 : b_hh1;
    f32x4 bI, bF, bG, bO;
#define LDB(dst, g) dst[0]=bi[g*64+j0]+bh[g*64+j0]; dst[1]=bi[g*64+j0+1]+bh[g*64+j0+1]; \
                    dst[2]=bi[g*64+j0+2]+bh[g*64+j0+2]; dst[3]=bi[g*64+j0+3]+bh[g*64+j0+3];
    LDB(bI, 0) LDB(bF, 1) LDB(bG, 2) LDB(bO, 3)
#undef LDB

    f32x4 cst = {0.f, 0.f, 0.f, 0.f};

    // zero state buffers
    {
        ushort* z0 = (ushort*)&h0sh[0][0][0];
        ushort* z1 = (ushort*)&h1sh[0][0][0];
        for (int i = tid; i < 2 * 16 * 72; i += 512) { z0[i] = 0; z1[i] = 0; }
    }

    // xg prefetch (L0 lanes): rows g*64 + j0.. for (batch, k)
    const ushort* xbase = xg + (size_t)(bb * 16 + b) * TT * 256 + j0;
    uint2 xc0={0,0},xc1={0,0},xc2={0,0},xc3={0,0};
    uint2 xn0={0,0},xn1={0,0},xn2={0,0},xn3={0,0};
    if (isL0) {
        xc0 = *(const uint2*)(xbase +   0); xc1 = *(const uint2*)(xbase +  64);
        xc2 = *(const uint2*)(xbase + 128); xc3 = *(const uint2*)(xbase + 192);
        xn0 = *(const uint2*)(xbase + 256 +   0); xn1 = *(const uint2*)(xbase + 256 +  64);
        xn2 = *(const uint2*)(xbase + 256 + 128); xn3 = *(const uint2*)(xbase + 256 + 192);
    }
    __syncthreads();

    ushort* h1b = h1g + (size_t)(bb * 16 + b) * TT * 64 + j0;

    for (int k = 0; k <= TT; ++k) {
        const int prv = (k + 1) & 1, cur = k & 1;
        if (isL0) {
            if (k < TT) {
                f32x4 ai = bI, af = bF, ag = bG, ao = bO;
#define ADDX(acc, xc) { h2 lo = BC(xc.x), hi = BC(xc.y); \
    acc[0] += (float)lo[0]; acc[1] += (float)lo[1]; \
    acc[2] += (float)hi[0]; acc[3] += (float)hi[1]; }
                ADDX(ai, xc0) ADDX(af, xc1) ADDX(ag, xc2) ADDX(ao, xc3)
#undef ADDX
                xc0 = xn0; xc1 = xn1; xc2 = xn2; xc3 = xn3;
                if (k + 2 < TT) {
                    const ushort* xp = xbase + (size_t)(k + 2) * 256;
                    xn0 = *(const uint2*)(xp +   0); xn1 = *(const uint2*)(xp +  64);
                    xn2 = *(const uint2*)(xp + 128); xn3 = *(const uint2*)(xp + 192);
                }
                const _Float16* hp = &h0sh[prv][b][qk];
                half8 v0 = *(const half8*)hp;
                half8 v1 = *(const half8*)(hp + 32);
                ai = MFMA16(F01, v1, MFMA16(F00, v0, ai));
                af = MFMA16(F11, v1, MFMA16(F10, v0, af));
                ag = MFMA16(F21, v1, MFMA16(F20, v0, ag));
                ao = MFMA16(F31, v1, MFMA16(F30, v0, ao));
                uint2 pk = lstm_act(ai, af, ag, ao, &cst);
                *(uint2*)&h0sh[cur][b][j0] = pk;
            }
        } else {
            if (k >= 1) {
                f32x4 ai = bI, af = bF, ag = bG, ao = bO;
                const _Float16* ap = &h0sh[prv][b][qk];   // h0(k-1)
                half8 v0 = *(const half8*)ap;
                half8 v1 = *(const half8*)(ap + 32);
                const _Float16* bp = &h1sh[cur][b][qk];   // h1(k-2)
                half8 v2 = *(const half8*)bp;
                half8 v3 = *(const half8*)(bp + 32);
                ai = MFMA16(F03, v3, MFMA16(F02, v2, MFMA16(F01, v1, MFMA16(F00, v0, ai))));
                af = MFMA16(F13, v3, MFMA16(F12, v2, MFMA16(F11, v1, MFMA16(F10, v0, af))));
                ag = MFMA16(F23, v3, MFMA16(F22, v2, MFMA16(F21, v1, MFMA16(F20, v0, ag))));
                ao = MFMA16(F33, v3, MFMA16(F32, v2, MFMA16(F31, v1, MFMA16(F30, v0, ao))));
                uint2 pk = lstm_act(ai, af, ag, ao, &cst);
                *(uint2*)&h1sh[prv][b][j0] = pk;          // h1(k-1)
                *(uint2*)(h1b + (size_t)(k - 1) * 64) = pk;
            }
        }
        __syncthreads();
    }
}

// ============ Kernel C: out[bt] = sigmoid(h1g[bt,:] . w_out + b_out) =========
__global__ __launch_bounds__(256)
void head_gemv(const ushort* __restrict__ h1g, const float* __restrict__ w_out,
               const float* __restrict__ b_out, float* __restrict__ outp)
{
    __shared__ float wsh[64];
    const int tid = threadIdx.x;
    if (tid < 64) wsh[tid] = w_out[tid];
    __syncthreads();
    const int bt = blockIdx.x * 256 + tid;
    const uint4* hp = (const uint4*)(h1g + (size_t)bt * 64);
    float s = 0.0f;
    #pragma unroll
    for (int i = 0; i < 8; ++i) {
        uint4 v = hp[i];
        const float* wp = &wsh[8 * i];
        h2 p;
        p = BC(v.x); s = fmaf((float)p[0], wp[0], s); s = fmaf((float)p[1], wp[1], s);
        p = BC(v.y); s = fmaf((float)p[0], wp[2], s); s = fmaf((float)p[1], wp[3], s);
        p = BC(v.z); s = fmaf((float)p[0], wp[4], s); s = fmaf((float)p[1], wp[5], s);
        p = BC(v.w); s = fmaf((float)p[0], wp[6], s); s = fmaf((float)p[1], wp[7], s);
    }
    outp[bt] = __builtin_amdgcn_rcpf(1.0f + __expf(-(s + b_out[0])));
}

extern "C" void kernel_launch(void* const* d_in, const int* in_sizes, int n_in,
                              void* d_out, int out_size, void* d_ws, size_t ws_size,
                              hipStream_t stream) {
    const float* x     = (const float*)d_in[0];
    const float* w_ih0 = (const float*)d_in[1];
    const float* w_hh0 = (const float*)d_in[2];
    const float* b_ih0 = (const float*)d_in[3];
    const float* b_hh0 = (const float*)d_in[4];
    const float* w_ih1 = (const float*)d_in[5];
    const float* w_hh1 = (const float*)d_in[6];
    const float* b_ih1 = (const float*)d_in[7];
    const float* b_hh1 = (const float*)d_in[8];
    const float* w_out = (const float*)d_in[9];
    const float* b_out = (const float*)d_in[10];
    float* out = (float*)d_out;

    ushort* xg  = (ushort*)d_ws;                                   // 128 MiB
    ushort* h1g = (ushort*)((char*)d_ws + (size_t)BT * 256 * 2);   //  32 MiB

    hipLaunchKernelGGL(xg_mfma, dim3(BT / 64), dim3(256), 0, stream, x, w_ih0, xg);
    hipLaunchKernelGGL(lstm2_core, dim3(NBLK), dim3(512), 0, stream,
                       w_hh0, b_ih0, b_hh0, w_ih1, w_hh1, b_ih1, b_hh1, xg, h1g);
    hipLaunchKernelGGL(head_gemv, dim3(BT / 256), dim3(256), 0, stream,
                       h1g, w_out, b_out, out);
}

// Round 9
// 999.601 us; speedup vs baseline: 1.1775x; 1.1775x over previous
//
#include <hip/hip_runtime.h>

#define BB 256
#define TT 1024
#define II 128
#define HH 64
#define BT (BB * TT)

typedef _Float16 h2 __attribute__((ext_vector_type(2)));
typedef _Float16 half8 __attribute__((ext_vector_type(8)));
typedef float f32x4 __attribute__((ext_vector_type(4)));
typedef unsigned int uint;
typedef unsigned short ushort;

#define DOT2(a, b, c) __builtin_amdgcn_fdot2((a), (b), (c), false)
#define BC(u) __builtin_bit_cast(h2, (uint)(u))
#define MFMA16(a, b, c) __builtin_amdgcn_mfma_f32_16x16x32_f16((a), (b), (c), 0, 0, 0)

// Drain-free barrier: LDS ordering only (lgkmcnt), NO vmcnt(0) drain.
// __syncthreads() compiles to "s_waitcnt vmcnt(0) lgkmcnt(0); s_barrier",
// which stalls every step on the HBM round-trip of the xg prefetch issued
// that same iteration (~900 cyc — R7/R8's hidden wall). Cross-wave data
// here flows only through LDS; global loads land in wave-private regs
// (compiler still emits vmcnt waits before use) and h1 stores are consumed
// by a later kernel. So lgkmcnt(0) alone is sufficient.
#define BAR() asm volatile("s_waitcnt lgkmcnt(0)\n\ts_barrier" ::: "memory")

#define LDPK(P, ptr) uint P; { float2 _f = *(const float2*)(ptr); \
    h2 _h; _h[0] = (_Float16)_f.x; _h[1] = (_Float16)_f.y; \
    P = __builtin_bit_cast(uint, _h); }
#define PIN8(a,b,c,d,e,f,g,h_) asm volatile("" : "+v"(a),"+v"(b),"+v"(c),"+v"(d),"+v"(e),"+v"(f),"+v"(g),"+v"(h_));
#define LD8(P, base, o) \
    LDPK(P##0,(base)+(o)+ 0) LDPK(P##1,(base)+(o)+ 2) LDPK(P##2,(base)+(o)+ 4) LDPK(P##3,(base)+(o)+ 6) \
    LDPK(P##4,(base)+(o)+ 8) LDPK(P##5,(base)+(o)+10) LDPK(P##6,(base)+(o)+12) LDPK(P##7,(base)+(o)+14) \
    PIN8(P##0,P##1,P##2,P##3,P##4,P##5,P##6,P##7)

#define D8(P, va, vb) \
    a0 = DOT2(BC(P##0), BC((va).x), a0); a1 = DOT2(BC(P##1), BC((va).y), a1); \
    a2 = DOT2(BC(P##2), BC((va).z), a2); a3 = DOT2(BC(P##3), BC((va).w), a3); \
    a0 = DOT2(BC(P##4), BC((vb).x), a0); a1 = DOT2(BC(P##5), BC((vb).y), a1); \
    a2 = DOT2(BC(P##6), BC((vb).z), a2); a3 = DOT2(BC(P##7), BC((vb).w), a3);

// ============ Kernel A: xg[bt][r] = x[bt,:] . w_ih0[r,:]  (f16) — R7, passed ====
__global__ __launch_bounds__(256)
void xg_mfma(const float* __restrict__ x, const float* __restrict__ w_ih0,
             ushort* __restrict__ xg)
{
    __shared__ __align__(16) _Float16 xt[64][136];
    __shared__ __align__(16) _Float16 wt[128][136];
    const int tid = threadIdx.x, lane = tid & 63, wv = tid >> 6;
    const int bt0 = blockIdx.x * 64;
    {
        const int row = tid >> 2, q = (tid & 3) * 32;
        const float4* src = (const float4*)(x + (size_t)(bt0 + row) * II + q);
        _Float16* dst = &xt[row][q];
        #pragma unroll
        for (int i = 0; i < 8; ++i) {
            float4 v = src[i];
            dst[4*i+0]=(_Float16)v.x; dst[4*i+1]=(_Float16)v.y;
            dst[4*i+2]=(_Float16)v.z; dst[4*i+3]=(_Float16)v.w;
        }
    }
    for (int nh = 0; nh < 2; ++nh) {
        __syncthreads();
        {
            const int n = tid >> 1, kh = (tid & 1) * 64;
            const float4* src = (const float4*)(w_ih0 + (size_t)(nh * 128 + n) * II + kh);
            _Float16* dst = &wt[n][kh];
            #pragma unroll
            for (int i = 0; i < 16; ++i) {
                float4 v = src[i];
                dst[4*i+0]=(_Float16)v.x; dst[4*i+1]=(_Float16)v.y;
                dst[4*i+2]=(_Float16)v.z; dst[4*i+3]=(_Float16)v.w;
            }
        }
        __syncthreads();
        const int m = wv * 16 + (lane & 15);
        const int kf = (lane >> 4) * 8;
        half8 a0 = *(const half8*)&xt[m][ 0 + kf];
        half8 a1 = *(const half8*)&xt[m][32 + kf];
        half8 a2 = *(const half8*)&xt[m][64 + kf];
        half8 a3 = *(const half8*)&xt[m][96 + kf];
        #pragma unroll
        for (int nt = 0; nt < 8; ++nt) {
            const int nloc = nt * 16 + (lane & 15);
            half8 b0 = *(const half8*)&wt[nloc][ 0 + kf];
            half8 b1 = *(const half8*)&wt[nloc][32 + kf];
            half8 b2 = *(const half8*)&wt[nloc][64 + kf];
            half8 b3 = *(const half8*)&wt[nloc][96 + kf];
            f32x4 acc = {0.f, 0.f, 0.f, 0.f};
            acc = MFMA16(a0, b0, acc); acc = MFMA16(a1, b1, acc);
            acc = MFMA16(a2, b2, acc); acc = MFMA16(a3, b3, acc);
            const int col = nh * 128 + nt * 16 + (lane & 15);
            const int r0  = wv * 16 + (lane >> 4) * 4;
            #pragma unroll
            for (int r = 0; r < 4; ++r) {
                _Float16 hv = (_Float16)acc[r];
                xg[(size_t)(bt0 + r0 + r) * 256 + col] = __builtin_bit_cast(ushort, hv);
            }
        }
    }
}

// ============ Kernel B: persistent 2-layer recurrence (R7 + drain-free barrier)
// 256 blocks x 512 thr (one batch element per block = one per CU).
// Waves 0-3: L0 h-recurrence (32 packs w_hh0). Waves 4-7: L1 (64 packs).
// xg prefetched 2 steps deep; h1 streamed to h1g. 1 barrier/step (lgkm-only).
__global__ __launch_bounds__(512) __attribute__((amdgpu_waves_per_eu(2, 2)))
void lstm2_core(const float* __restrict__ w_hh0,
                const float* __restrict__ b_ih0, const float* __restrict__ b_hh0,
                const float* __restrict__ w_ih1, const float* __restrict__ w_hh1,
                const float* __restrict__ b_ih1, const float* __restrict__ b_hh1,
                const ushort* __restrict__ xg, ushort* __restrict__ h1g)
{
    const int bb  = blockIdx.x;
    const int tid = threadIdx.x;
    const int w   = tid >> 6;
    const int l   = tid & 63;
    const int g   = l >> 4;                    // gate 0..3 (i,f,g,o)
    const int j   = 16 * (w & 3) + (l & 15);   // hidden index
    const int r   = g * 64 + j;                // gate-matrix row
    const bool isL0 = (w < 4);

    __shared__ __align__(16) uint h0sh[2][32];
    __shared__ __align__(16) uint h1sh[2][32];

    const float* qA = isL0 ? (w_hh0 + (size_t)r * HH) : (w_ih1 + (size_t)r * HH);
    const float* qB = isL0 ? (w_hh0 + (size_t)r * HH) : (w_hh1 + (size_t)r * HH);
    LD8(G0, qA,  0) LD8(G1, qA, 16) LD8(G2, qA, 32) LD8(G3, qA, 48)
    LD8(G4, qB,  0) LD8(G5, qB, 16) LD8(G6, qB, 32) LD8(G7, qB, 48)

    float bias = isL0 ? (b_ih0[r] + b_hh0[r]) : (b_ih1[r] + b_hh1[r]);
    // unified activation: act = (a*y + b) * rcp(y+1), y = exp(n*pre)
    const float nsc = (g == 2) ?  2.0f : -1.0f;
    const float aco = (g == 2) ?  1.0f :  0.0f;
    const float bco = (g == 2) ? -1.0f :  1.0f;

    float cst = 0.0f;
    const ushort* xgb = xg + (size_t)bb * TT * 256 + r;   // L0 lanes only
    ushort* h1b = h1g + (size_t)bb * TT * 64;

    if (tid < 32)      h0sh[1][tid] = 0u;
    else if (tid < 64) h1sh[1][tid - 32] = 0u;
    __syncthreads();

    ushort xcur = 0, xn1 = 0, xn2 = 0;
    if (isL0) { xcur = xgb[0]; xn1 = xgb[256]; }

    for (int k = 0; k <= TT; ++k) {
        if (isL0 && k + 2 < TT) xn2 = xgb[(size_t)(k + 2) * 256];

        const bool active = isL0 ? (k < TT) : (k >= 1);
        if (active) {
            float a0 = 0.f, a1 = 0.f, a2 = 0.f, a3 = 0.f;
            if (isL0) {
                // h0(k) = lstm0(xg(k), h0(k-1))
                const uint4* hq = (const uint4*)&h0sh[(k + 1) & 1][0];
                uint4 v0, v1;
                v0 = hq[0]; v1 = hq[1]; D8(G0, v0, v1)
                v0 = hq[2]; v1 = hq[3]; D8(G1, v0, v1)
                v0 = hq[4]; v1 = hq[5]; D8(G2, v0, v1)
                v0 = hq[6]; v1 = hq[7]; D8(G3, v0, v1)
            } else {
                // h1(k-1) = lstm1(h0(k-1), h1(k-2))
                const uint4* aq = (const uint4*)&h0sh[(k + 1) & 1][0];
                const uint4* bq = (const uint4*)&h1sh[k & 1][0];
                uint4 v0, v1;
                v0 = aq[0]; v1 = aq[1]; D8(G0, v0, v1)
                v0 = aq[2]; v1 = aq[3]; D8(G1, v0, v1)
                v0 = aq[4]; v1 = aq[5]; D8(G2, v0, v1)
                v0 = aq[6]; v1 = aq[7]; D8(G3, v0, v1)
                v0 = bq[0]; v1 = bq[1]; D8(G4, v0, v1)
                v0 = bq[2]; v1 = bq[3]; D8(G5, v0, v1)
                v0 = bq[4]; v1 = bq[5]; D8(G6, v0, v1)
                v0 = bq[6]; v1 = bq[7]; D8(G7, v0, v1)
            }
            float pre = ((a0 + a1) + (a2 + a3)) + bias;
            if (isL0) pre += (float)__builtin_bit_cast(_Float16, xcur);
            float y   = __expf(nsc * pre);
            float rr  = __builtin_amdgcn_rcpf(y + 1.0f);
            float act = fmaf(aco, y, bco) * rr;
            // gather gates of own j across lanes l^16, l^32, l^48
            float s0 = act;
            float s1 = __shfl_xor(s0, 16, 64);
            float s2 = __shfl_xor(s0, 32, 64);
            float s3 = __shfl_xor(s1, 32, 64);
            const bool gb0 = (g & 1) != 0, gb1 = (g & 2) != 0;
            float pig = gb0 ? s1 * s3 : s0 * s2;                 // i * g
            float ff  = gb0 ? (gb1 ? s2 : s0) : (gb1 ? s3 : s1); // f
            float oo  = gb0 ? (gb1 ? s0 : s2) : (gb1 ? s1 : s3); // o
            cst = fmaf(ff, cst, pig);
            float y2 = __expf(2.0f * cst);
            float th = (y2 - 1.0f) * __builtin_amdgcn_rcpf(y2 + 1.0f);
            float hval = oo * th;
            if (g == 0) {
                _Float16 hf = (_Float16)hval;
                if (isL0) {
                    ((_Float16*)&h0sh[k & 1][0])[j] = hf;
                } else {
                    ((_Float16*)&h1sh[(k - 1) & 1][0])[j] = hf;
                    h1b[(size_t)(k - 1) * 64 + j] = __builtin_bit_cast(ushort, hf);
                }
            }
        }
        xcur = xn1; xn1 = xn2;
        BAR();      // lgkmcnt-only barrier — no vmcnt drain of xg/h1 traffic
    }
}

// ============ Kernel C: out[bt] = sigmoid(h1g[bt,:] . w_out + b_out) =========
__global__ __launch_bounds__(256)
void head_gemv(const ushort* __restrict__ h1g, const float* __restrict__ w_out,
               const float* __restrict__ b_out, float* __restrict__ outp)
{
    __shared__ float wsh[64];
    const int tid = threadIdx.x;
    if (tid < 64) wsh[tid] = w_out[tid];
    __syncthreads();
    const int bt = blockIdx.x * 256 + tid;
    const uint4* hp = (const uint4*)(h1g + (size_t)bt * 64);
    float s = 0.0f;
    #pragma unroll
    for (int i = 0; i < 8; ++i) {
        uint4 v = hp[i];
        const float* wp = &wsh[8 * i];
        h2 p;
        p = BC(v.x); s = fmaf((float)p[0], wp[0], s); s = fmaf((float)p[1], wp[1], s);
        p = BC(v.y); s = fmaf((float)p[0], wp[2], s); s = fmaf((float)p[1], wp[3], s);
        p = BC(v.z); s = fmaf((float)p[0], wp[4], s); s = fmaf((float)p[1], wp[5], s);
        p = BC(v.w); s = fmaf((float)p[0], wp[6], s); s = fmaf((float)p[1], wp[7], s);
    }
    outp[bt] = __builtin_amdgcn_rcpf(1.0f + __expf(-(s + b_out[0])));
}

extern "C" void kernel_launch(void* const* d_in, const int* in_sizes, int n_in,
                              void* d_out, int out_size, void* d_ws, size_t ws_size,
                              hipStream_t stream) {
    const float* x     = (const float*)d_in[0];
    const float* w_ih0 = (const float*)d_in[1];
    const float* w_hh0 = (const float*)d_in[2];
    const float* b_ih0 = (const float*)d_in[3];
    const float* b_hh0 = (const float*)d_in[4];
    const float* w_ih1 = (const float*)d_in[5];
    const float* w_hh1 = (const float*)d_in[6];
    const float* b_ih1 = (const float*)d_in[7];
    const float* b_hh1 = (const float*)d_in[8];
    const float* w_out = (const float*)d_in[9];
    const float* b_out = (const float*)d_in[10];
    float* out = (float*)d_out;

    ushort* xg  = (ushort*)d_ws;                                   // 128 MiB
    ushort* h1g = (ushort*)((char*)d_ws + (size_t)BT * 256 * 2);   //  32 MiB

    hipLaunchKernelGGL(xg_mfma, dim3(BT / 64), dim3(256), 0, stream, x, w_ih0, xg);
    hipLaunchKernelGGL(lstm2_core, dim3(BB), dim3(512), 0, stream,
                       w_hh0, b_ih0, b_hh0, w_ih1, w_hh1, b_ih1, b_hh1, xg, h1g);
    hipLaunchKernelGGL(head_gemv, dim3(BT / 256), dim3(256), 0, stream,
                       h1g, w_out, b_out, out);
}

// Round 10
// 823.080 us; speedup vs baseline: 1.4300x; 1.2145x over previous
//
#include <hip/hip_runtime.h>

#define BB 256
#define TT 1024
#define II 128
#define HH 64
#define BT (BB * TT)

typedef _Float16 h2 __attribute__((ext_vector_type(2)));
typedef _Float16 half8 __attribute__((ext_vector_type(8)));
typedef float f32x4 __attribute__((ext_vector_type(4)));
typedef unsigned int uint;
typedef unsigned short ushort;

#define DOT2(a, b, c) __builtin_amdgcn_fdot2((a), (b), (c), false)
#define BC(u) __builtin_bit_cast(h2, (uint)(u))
#define MFMA16(a, b, c) __builtin_amdgcn_mfma_f32_16x16x32_f16((a), (b), (c), 0, 0, 0)
#define SIG(v) __builtin_amdgcn_rcpf(1.0f + __expf(-(v)))
#define TNH(v) (1.0f - 2.0f * __builtin_amdgcn_rcpf(1.0f + __expf(2.0f * (v))))

// lgkm-only barrier (R9): cross-wave data flows through LDS only.
#define BAR() asm volatile("s_waitcnt lgkmcnt(0)\n\ts_barrier" ::: "memory")

#define LDPK(P, ptr) uint P; { float2 _f = *(const float2*)(ptr); \
    h2 _h; _h[0] = (_Float16)_f.x; _h[1] = (_Float16)_f.y; \
    P = __builtin_bit_cast(uint, _h); }
#define PIN8(a,b,c,d,e,f,g,h_) asm volatile("" : "+v"(a),"+v"(b),"+v"(c),"+v"(d),"+v"(e),"+v"(f),"+v"(g),"+v"(h_));
#define LD8(P, base, o) \
    LDPK(P##0,(base)+(o)+ 0) LDPK(P##1,(base)+(o)+ 2) LDPK(P##2,(base)+(o)+ 4) LDPK(P##3,(base)+(o)+ 6) \
    LDPK(P##4,(base)+(o)+ 8) LDPK(P##5,(base)+(o)+10) LDPK(P##6,(base)+(o)+12) LDPK(P##7,(base)+(o)+14) \
    PIN8(P##0,P##1,P##2,P##3,P##4,P##5,P##6,P##7)

// 8 packs vs 2 broadcast uint4 (16 vals) into explicit acc chain c0..c3
#define D8A(P, va, vb, c0, c1, c2, c3) \
    c0 = DOT2(BC(P##0), BC((va).x), c0); c1 = DOT2(BC(P##1), BC((va).y), c1); \
    c2 = DOT2(BC(P##2), BC((va).z), c2); c3 = DOT2(BC(P##3), BC((va).w), c3); \
    c0 = DOT2(BC(P##4), BC((vb).x), c0); c1 = DOT2(BC(P##5), BC((vb).y), c1); \
    c2 = DOT2(BC(P##6), BC((vb).z), c2); c3 = DOT2(BC(P##7), BC((vb).w), c3);

// full 64-wide row dot for gate: 4 x D8A over hv0..hv7
#define GDOT(G, s) { float a0=0.f,a1=0.f,a2=0.f,a3=0.f; \
    D8A(G##A, hv0, hv1, a0,a1,a2,a3) D8A(G##B, hv2, hv3, a0,a1,a2,a3) \
    D8A(G##C, hv4, hv5, a0,a1,a2,a3) D8A(G##D, hv6, hv7, a0,a1,a2,a3) \
    s = (a0 + a1) + (a2 + a3); }

// ============ Kernel A: xg[bt][j][g] = x[bt,:] . w_ih0[g*64+j,:]  (f16) ======
// (R7's verified MFMA kernel; store re-indexed to [bt][j*4+g] so the core's
//  P-wave reads one coalesced dwordx2 per lane per step.)
__global__ __launch_bounds__(256)
void xg_mfma(const float* __restrict__ x, const float* __restrict__ w_ih0,
             ushort* __restrict__ xg)
{
    __shared__ __align__(16) _Float16 xt[64][136];
    __shared__ __align__(16) _Float16 wt[128][136];
    const int tid = threadIdx.x, lane = tid & 63, wv = tid >> 6;
    const int bt0 = blockIdx.x * 64;
    {
        const int row = tid >> 2, q = (tid & 3) * 32;
        const float4* src = (const float4*)(x + (size_t)(bt0 + row) * II + q);
        _Float16* dst = &xt[row][q];
        #pragma unroll
        for (int i = 0; i < 8; ++i) {
            float4 v = src[i];
            dst[4*i+0]=(_Float16)v.x; dst[4*i+1]=(_Float16)v.y;
            dst[4*i+2]=(_Float16)v.z; dst[4*i+3]=(_Float16)v.w;
        }
    }
    for (int nh = 0; nh < 2; ++nh) {
        __syncthreads();
        {
            const int n = tid >> 1, kh = (tid & 1) * 64;
            const float4* src = (const float4*)(w_ih0 + (size_t)(nh * 128 + n) * II + kh);
            _Float16* dst = &wt[n][kh];
            #pragma unroll
            for (int i = 0; i < 16; ++i) {
                float4 v = src[i];
                dst[4*i+0]=(_Float16)v.x; dst[4*i+1]=(_Float16)v.y;
                dst[4*i+2]=(_Float16)v.z; dst[4*i+3]=(_Float16)v.w;
            }
        }
        __syncthreads();
        const int m = wv * 16 + (lane & 15);
        const int kf = (lane >> 4) * 8;
        half8 a0 = *(const half8*)&xt[m][ 0 + kf];
        half8 a1 = *(const half8*)&xt[m][32 + kf];
        half8 a2 = *(const half8*)&xt[m][64 + kf];
        half8 a3 = *(const half8*)&xt[m][96 + kf];
        #pragma unroll
        for (int nt = 0; nt < 8; ++nt) {
            const int nloc = nt * 16 + (lane & 15);
            half8 b0 = *(const half8*)&wt[nloc][ 0 + kf];
            half8 b1 = *(const half8*)&wt[nloc][32 + kf];
            half8 b2 = *(const half8*)&wt[nloc][64 + kf];
            half8 b3 = *(const half8*)&wt[nloc][96 + kf];
            f32x4 acc = {0.f, 0.f, 0.f, 0.f};
            acc = MFMA16(a0, b0, acc); acc = MFMA16(a1, b1, acc);
            acc = MFMA16(a2, b2, acc); acc = MFMA16(a3, b3, acc);
            const int col = nh * 128 + nt * 16 + (lane & 15);   // gate-row r
            const int idx = (col & 63) * 4 + (col >> 6);        // -> [j*4+g]
            const int r0  = wv * 16 + (lane >> 4) * 4;
            #pragma unroll
            for (int r = 0; r < 4; ++r) {
                _Float16 hv = (_Float16)acc[r];
                xg[(size_t)(bt0 + r0 + r) * 256 + idx] = __builtin_bit_cast(ushort, hv);
            }
        }
    }
}

// ============ Kernel B: 3-wave pipelined recurrence, 1 block per batch elem ==
// Wave 0 (P):  h0(k)   = lstm0(xg(k), h0(k-1))            [W_hh0 in-lane]
// Wave 1 (Q1): z(k-1)  = W_ih1 . h0(k-1)                  [W_ih1 in-lane]
// Wave 2 (Q2): h1(k-2) = act(z(k-2) + W_hh1.h1(k-3) + b)  [W_hh1 in-lane]
// Lane j owns ALL 4 gate rows of hidden j (128 packs) -> zero shuffles.
// Every cross-wave edge crosses >=1 barrier -> per-step critical path is one
// wave's own body, not a chained sum (R9 lesson: same-step coupling was the
// stall). All cross-wave data via LDS; BAR() is lgkm-only.
__global__ __launch_bounds__(192) __attribute__((amdgpu_waves_per_eu(1, 1)))
void lstm2_core(const float* __restrict__ w_hh0,
                const float* __restrict__ b_ih0, const float* __restrict__ b_hh0,
                const float* __restrict__ w_ih1, const float* __restrict__ w_hh1,
                const float* __restrict__ b_ih1, const float* __restrict__ b_hh1,
                const ushort* __restrict__ xg, ushort* __restrict__ h1g)
{
    const int bb = blockIdx.x;
    const int w  = threadIdx.x >> 6;
    const int j  = threadIdx.x & 63;

    __shared__ __align__(16) uint  h0buf[2][32];   // 64 f16
    __shared__ __align__(16) uint  h1buf[2][32];
    __shared__ float zbuf[2][4][68];               // f32, padded

    // ---- weights: all three waves load a [256][64] matrix, 4 rows/lane ----
    const float* Wsel = (w == 0) ? w_hh0 : (w == 1) ? w_ih1 : w_hh1;
    const float* r0p = Wsel + (size_t)(  0 + j) * 64;
    const float* r1p = Wsel + (size_t)( 64 + j) * 64;
    const float* r2p = Wsel + (size_t)(128 + j) * 64;
    const float* r3p = Wsel + (size_t)(192 + j) * 64;
    LD8(G0A, r0p,  0) LD8(G0B, r0p, 16) LD8(G0C, r0p, 32) LD8(G0D, r0p, 48)
    LD8(G1A, r1p,  0) LD8(G1B, r1p, 16) LD8(G1C, r1p, 32) LD8(G1D, r1p, 48)
    LD8(G2A, r2p,  0) LD8(G2B, r2p, 16) LD8(G2C, r2p, 32) LD8(G2D, r2p, 48)
    LD8(G3A, r3p,  0) LD8(G3B, r3p, 16) LD8(G3C, r3p, 32) LD8(G3D, r3p, 48)

    // biases (P: layer0, Q2: layer1, Q1: unused zeros)
    float bI = 0.f, bF = 0.f, bG = 0.f, bO = 0.f;
    if (w == 0) {
        bI = b_ih0[j]       + b_hh0[j];
        bF = b_ih0[64 + j]  + b_hh0[64 + j];
        bG = b_ih0[128 + j] + b_hh0[128 + j];
        bO = b_ih0[192 + j] + b_hh0[192 + j];
    } else if (w == 2) {
        bI = b_ih1[j]       + b_hh1[j];
        bF = b_ih1[64 + j]  + b_hh1[64 + j];
        bG = b_ih1[128 + j] + b_hh1[128 + j];
        bO = b_ih1[192 + j] + b_hh1[192 + j];
    }

    float cst = 0.0f;
    const ushort* xbase = xg + (size_t)bb * TT * 256 + j * 4;
    ushort* h1b = h1g + (size_t)bb * TT * 64 + j;

    if (threadIdx.x < 32)       h0buf[1][threadIdx.x] = 0u;
    else if (threadIdx.x < 64)  h1buf[1][threadIdx.x - 32] = 0u;
    __syncthreads();

    uint2 xc = {0,0}, xn1 = {0,0}, xn2 = {0,0};
    if (w == 0) {
        xc  = *(const uint2*)(xbase);
        xn1 = *(const uint2*)(xbase + 256);
    }

    for (int k = 0; k < TT + 2; ++k) {
        if (w == 0) {
            if (k + 2 < TT) xn2 = *(const uint2*)(xbase + (size_t)(k + 2) * 256);
            if (k < TT) {
                const uint4* hq = (const uint4*)&h0buf[(k + 1) & 1][0];
                uint4 hv0=hq[0], hv1=hq[1], hv2=hq[2], hv3=hq[3];
                uint4 hv4=hq[4], hv5=hq[5], hv6=hq[6], hv7=hq[7];
                float si, sf, sg, so;
                GDOT(G0, si) GDOT(G1, sf) GDOT(G2, sg) GDOT(G3, so)
                h2 xlo = BC(xc.x), xhi = BC(xc.y);   // [i,f] [g,o]
                si += bI + (float)xlo[0]; sf += bF + (float)xlo[1];
                sg += bG + (float)xhi[0]; so += bO + (float)xhi[1];
                float ii = SIG(si), ff = SIG(sf), gg = TNH(sg), oo = SIG(so);
                cst = fmaf(ff, cst, ii * gg);
                float hval = oo * TNH(cst);
                ((_Float16*)&h0buf[k & 1][0])[j] = (_Float16)hval;
            }
            xc = xn1; xn1 = xn2;
        } else if (w == 1) {
            if (k >= 1 && k <= TT) {
                const int m = k - 1;
                const uint4* hq = (const uint4*)&h0buf[m & 1][0];
                uint4 hv0=hq[0], hv1=hq[1], hv2=hq[2], hv3=hq[3];
                uint4 hv4=hq[4], hv5=hq[5], hv6=hq[6], hv7=hq[7];
                float si, sf, sg, so;
                GDOT(G0, si) GDOT(G1, sf) GDOT(G2, sg) GDOT(G3, so)
                const int s = m & 1;
                zbuf[s][0][j] = si; zbuf[s][1][j] = sf;
                zbuf[s][2][j] = sg; zbuf[s][3][j] = so;
            }
        } else {
            if (k >= 2) {
                const int m = k - 2;
                const int s = m & 1;
                const uint4* hq = (const uint4*)&h1buf[(m + 1) & 1][0];  // h1(m-1)
                uint4 hv0=hq[0], hv1=hq[1], hv2=hq[2], hv3=hq[3];
                uint4 hv4=hq[4], hv5=hq[5], hv6=hq[6], hv7=hq[7];
                float si, sf, sg, so;
                GDOT(G0, si) GDOT(G1, sf) GDOT(G2, sg) GDOT(G3, so)
                si += bI + zbuf[s][0][j]; sf += bF + zbuf[s][1][j];
                sg += bG + zbuf[s][2][j]; so += bO + zbuf[s][3][j];
                float ii = SIG(si), ff = SIG(sf), gg = TNH(sg), oo = SIG(so);
                cst = fmaf(ff, cst, ii * gg);
                float hval = oo * TNH(cst);
                _Float16 hf = (_Float16)hval;
                ((_Float16*)&h1buf[m & 1][0])[j] = hf;
                h1b[(size_t)m * 64] = __builtin_bit_cast(ushort, hf);
            }
        }
        BAR();
    }
}

// ============ Kernel C: out[bt] = sigmoid(h1g[bt,:] . w_out + b_out) =========
__global__ __launch_bounds__(256)
void head_gemv(const ushort* __restrict__ h1g, const float* __restrict__ w_out,
               const float* __restrict__ b_out, float* __restrict__ outp)
{
    __shared__ float wsh[64];
    const int tid = threadIdx.x;
    if (tid < 64) wsh[tid] = w_out[tid];
    __syncthreads();
    const int bt = blockIdx.x * 256 + tid;
    const uint4* hp = (const uint4*)(h1g + (size_t)bt * 64);
    float s = 0.0f;
    #pragma unroll
    for (int i = 0; i < 8; ++i) {
        uint4 v = hp[i];
        const float* wp = &wsh[8 * i];
        h2 p;
        p = BC(v.x); s = fmaf((float)p[0], wp[0], s); s = fmaf((float)p[1], wp[1], s);
        p = BC(v.y); s = fmaf((float)p[0], wp[2], s); s = fmaf((float)p[1], wp[3], s);
        p = BC(v.z); s = fmaf((float)p[0], wp[4], s); s = fmaf((float)p[1], wp[5], s);
        p = BC(v.w); s = fmaf((float)p[0], wp[6], s); s = fmaf((float)p[1], wp[7], s);
    }
    outp[bt] = __builtin_amdgcn_rcpf(1.0f + __expf(-(s + b_out[0])));
}

extern "C" void kernel_launch(void* const* d_in, const int* in_sizes, int n_in,
                              void* d_out, int out_size, void* d_ws, size_t ws_size,
                              hipStream_t stream) {
    const float* x     = (const float*)d_in[0];
    const float* w_ih0 = (const float*)d_in[1];
    const float* w_hh0 = (const float*)d_in[2];
    const float* b_ih0 = (const float*)d_in[3];
    const float* b_hh0 = (const float*)d_in[4];
    const float* w_ih1 = (const float*)d_in[5];
    const float* w_hh1 = (const float*)d_in[6];
    const float* b_ih1 = (const float*)d_in[7];
    const float* b_hh1 = (const float*)d_in[8];
    const float* w_out = (const float*)d_in[9];
    const float* b_out = (const float*)d_in[10];
    float* out = (float*)d_out;

    ushort* xg  = (ushort*)d_ws;                                   // 128 MiB
    ushort* h1g = (ushort*)((char*)d_ws + (size_t)BT * 256 * 2);   //  32 MiB

    hipLaunchKernelGGL(xg_mfma, dim3(BT / 64), dim3(256), 0, stream, x, w_ih0, xg);
    hipLaunchKernelGGL(lstm2_core, dim3(BB), dim3(192), 0, stream,
                       w_hh0, b_ih0, b_hh0, w_ih1, w_hh1, b_ih1, b_hh1, xg, h1g);
    hipLaunchKernelGGL(head_gemv, dim3(BT / 256), dim3(256), 0, stream,
                       h1g, w_out, b_out, out);
}